// Round 1
// 212.233 us; speedup vs baseline: 1.0208x; 1.0208x over previous
//
#include <hip/hip_runtime.h>
#include <stdint.h>

#define NN 50000
#define NE 800000
#define NBK 512          // dst buckets
#define NPB 98           // nodes per bucket (512*98 = 50176 >= 50000)
#define BUCKCAP 2048     // edges per bucket region; mean 1568 -> 12 sigma margin
// layer1: in=128 hid=256; layer2: in=256 out=128
// Layer-2 restructured: out = mean_agg(h @ W2_l^T) + (h @ W2_r^T + b2)
// R5: never fuse gather phase into MFMA kernel. R7: scatter atomics op-count-bound.
// R8: m97-style global_load_lds staging + XOR swizzle (R10: conflicts -> 0).
// R10 lesson: 64-row tile re-stages full B per block (100 MB L2) and does too few
//   MFMAs per barrier drain -> 128x256 tile, 8 waves, B re-staging halved.
// R11 (this round): prep folded into mega (+hipMemsetAsync for bcur) -> -1 dispatch;
//   pass2agg1 dynamic node counter (fix 3-vs-4 node worker imbalance);
//   agg2 stages neighbor lists in LDS (removes 16x-redundant scalar VMEM loads).

typedef __bf16 bf16x8 __attribute__((ext_vector_type(8)));
typedef float  f32x4  __attribute__((ext_vector_type(4)));

__device__ __forceinline__ unsigned short f2bf(float f) {
    unsigned int u = __float_as_uint(f);
    unsigned int r = (u + 0x7fffu + ((u >> 16) & 1u)) >> 16;   // RNE
    return (unsigned short)r;
}
__device__ __forceinline__ float bf_lo(unsigned int v) { return __uint_as_float(v << 16); }
__device__ __forceinline__ float bf_hi(unsigned int v) { return __uint_as_float(v & 0xffff0000u); }

// async global->LDS, 16 B per lane; lds base wave-uniform, lane i lands at base+16i
__device__ __forceinline__ void gl_lds16(const void* g, void* l) {
    __builtin_amdgcn_global_load_lds(
        (const __attribute__((address_space(1))) void*)g,
        (__attribute__((address_space(3))) void*)l, 16, 0, 0);
}

// ---------------- mega: bucket bin-scatter + B-pack + cast_x in one dispatch ----------------
#define FILL_NB 391
#define PACK_NB 512
#define CAST_NB 6250
__global__ __launch_bounds__(256) void mega_kernel(
    const int* __restrict__ edges,
    int* __restrict__ bcur, unsigned int* __restrict__ packed,
    const float* __restrict__ x, unsigned short* __restrict__ x_bf,
    const float* __restrict__ W1l, const float* __restrict__ W1r,
    const float* __restrict__ W2l, const float* __restrict__ W2r,
    unsigned short* __restrict__ B1, unsigned short* __restrict__ B2) {
    __shared__ int hist[NBK];
    __shared__ int scn[NBK];
    __shared__ int gbase[NBK];
    __shared__ int lcur[NBK];
    __shared__ int ps[256];
    __shared__ unsigned int sortbuf[2048];
    __shared__ int gaddrbuf[2048];
    __shared__ int nz;
    int b = blockIdx.x;
    int t = threadIdx.x;
    if (b < FILL_NB) {
        const int E = NE;
        if (t == 0) nz = 0;
        hist[t] = 0; hist[t + 256] = 0;
        __syncthreads();
        int accv = 0;
        for (int i = t; i < 512; i += 256) accv |= edges[2 * i + 1];
        if (accv) atomicOr(&nz, 1);
        __syncthreads();
        int f = nz ? 0 : 1;   // 1 => int64 storage

        int blockbase = b * 2048;
        int nedge = E - blockbase; if (nedge > 2048) nedge = 2048;
        unsigned int pk[8]; int bk[8];
#pragma unroll
        for (int u = 0; u < 8; ++u) {
            int lin = u * 256 + t;
            bk[u] = -1;
            if (lin < nedge) {
                int e = blockbase + lin;
                int src = edges[(size_t)e << f];
                int dst = edges[(size_t)(E + e) << f];
                int bb = dst / NPB;
                pk[u] = (unsigned int)src | ((unsigned int)(dst - bb * NPB) << 16);
                bk[u] = bb;
                atomicAdd(&hist[bb], 1);
            }
        }
        __syncthreads();
        int h0 = hist[2 * t], h1 = hist[2 * t + 1];
        int s = h0 + h1;
        ps[t] = s;
        __syncthreads();
        for (int off = 1; off < 256; off <<= 1) {
            int v = (t >= off) ? ps[t - off] : 0;
            __syncthreads();
            ps[t] += v;
            __syncthreads();
        }
        int excl = ps[t] - s;
        scn[2 * t] = excl;
        scn[2 * t + 1] = excl + h0;
        if (h0) gbase[2 * t] = atomicAdd(&bcur[2 * t], h0);
        if (h1) gbase[2 * t + 1] = atomicAdd(&bcur[2 * t + 1], h1);
        lcur[2 * t] = excl;
        lcur[2 * t + 1] = excl + h0;
        __syncthreads();
#pragma unroll
        for (int u = 0; u < 8; ++u) {
            if (bk[u] >= 0) {
                int p = atomicAdd(&lcur[bk[u]], 1);
                sortbuf[p] = pk[u];
                int off = gbase[bk[u]] + (p - scn[bk[u]]);
                gaddrbuf[p] = (off < BUCKCAP) ? (bk[u] * BUCKCAP + off) : -1;
            }
        }
        __syncthreads();
        for (int j = t; j < nedge; j += 256) {
            int a = gaddrbuf[j];
            if (a >= 0) packed[a] = sortbuf[j];
        }
    } else if (b < FILL_NB + PACK_NB) {
        int idx = (b - FILL_NB) * 256 + t;   // 0..131071
        if (idx < 65536) {
            int o = idx >> 8, k = idx & 255;
            float v = (k < 128) ? W1l[o * 128 + k] : W1r[o * 128 + (k - 128)];
            B1[idx] = f2bf(v);
        } else {
            int j = idx - 65536;
            int o = j >> 8, k = j & 255;
            float v = (o < 128) ? W2l[o * 256 + k] : W2r[(o - 128) * 256 + k];
            B2[j] = f2bf(v);
        }
    } else {
        int i4 = (b - FILL_NB - PACK_NB) * 256 + t;   // one float4 each
        float4 v = *(const float4*)(x + (size_t)i4 * 4);
        uint2 p;
        p.x = (unsigned int)f2bf(v.x) | ((unsigned int)f2bf(v.y) << 16);
        p.y = (unsigned int)f2bf(v.z) | ((unsigned int)f2bf(v.w) << 16);
        *(uint2*)(x_bf + (size_t)i4 * 4) = p;
    }
}

// ---------------- pass2+agg1 fused: per-bucket counting sort -> LDS lists -> mean1 ----------
__global__ __launch_bounds__(512) void pass2agg1_kernel(
    const unsigned int* __restrict__ packed, const int* __restrict__ bcur,
    const unsigned short* __restrict__ X,
    unsigned short* __restrict__ nbr, int* __restrict__ row_start, int* __restrict__ deg,
    unsigned short* __restrict__ mean) {
    __shared__ int hist[NPB];
    __shared__ int scn[NPB];
    __shared__ int lcur[NPB];
    __shared__ unsigned short lists[BUCKCAP];
    __shared__ int nodectr;
    int b = blockIdx.x;
    int t = threadIdx.x;
    int ne = bcur[b]; if (ne > BUCKCAP) ne = BUCKCAP;
    if (t < NPB) hist[t] = 0;
    if (t == 0) nodectr = 0;
    __syncthreads();
    const unsigned int* pb = packed + (size_t)b * BUCKCAP;
    for (int j = t; j < ne; j += 512) atomicAdd(&hist[pb[j] >> 16], 1);
    __syncthreads();
    if (t == 0) {
        int a = 0;
        for (int i = 0; i < NPB; ++i) { scn[i] = a; a += hist[i]; }
    }
    __syncthreads();
    if (t < NPB) lcur[t] = scn[t];
    __syncthreads();
    for (int j = t; j < ne; j += 512) {
        unsigned int w = pb[j];
        int p = atomicAdd(&lcur[w >> 16], 1);
        lists[p] = (unsigned short)(w & 0xffffu);   // src < 50000 < 65536
    }
    __syncthreads();
    if (t < NPB) {
        int node = b * NPB + t;
        if (node < NN) {
            row_start[node] = b * BUCKCAP + scn[t];
            deg[node] = hist[t];
        }
    }
    for (int j = t; j < ne; j += 512) nbr[(size_t)b * BUCKCAP + j] = lists[j];
    int l = t & 15;
    // dynamic node assignment: workers (16-lane groups) grab nodes via LDS counter,
    // removing the 3-vs-4-nodes static imbalance across the 32 workers.
    for (;;) {
        int n = 0;
        if (l == 0) n = atomicAdd(&nodectr, 1);
        n = __shfl(n, 0, 16);
        if (n >= NPB) break;
        int node = b * NPB + n;
        if (node >= NN) break;     // monotone counter: all later n are invalid too
        int dg = hist[n];
        const unsigned short* sl = &lists[scn[n]];
        float a0 = 0.f, a1 = 0.f, a2 = 0.f, a3 = 0.f, a4 = 0.f, a5 = 0.f, a6 = 0.f, a7 = 0.f;
        int i = 0;
        for (; i + 8 <= dg; i += 8) {
            uint4 v[8];
#pragma unroll
            for (int u = 0; u < 8; ++u) {
                int s = sl[i + u];
                v[u] = *(const uint4*)(X + ((size_t)s << 7) + l * 8);
            }
#pragma unroll
            for (int u = 0; u < 8; ++u) {
                a0 += bf_lo(v[u].x); a1 += bf_hi(v[u].x);
                a2 += bf_lo(v[u].y); a3 += bf_hi(v[u].y);
                a4 += bf_lo(v[u].z); a5 += bf_hi(v[u].z);
                a6 += bf_lo(v[u].w); a7 += bf_hi(v[u].w);
            }
        }
        for (; i < dg; ++i) {
            int s = sl[i];
            uint4 v = *(const uint4*)(X + ((size_t)s << 7) + l * 8);
            a0 += bf_lo(v.x); a1 += bf_hi(v.x);
            a2 += bf_lo(v.y); a3 += bf_hi(v.y);
            a4 += bf_lo(v.z); a5 += bf_hi(v.z);
            a6 += bf_lo(v.w); a7 += bf_hi(v.w);
        }
        float inv = 1.0f / (float)(dg > 1 ? dg : 1);
        uint4 p;
        p.x = (unsigned int)f2bf(a0 * inv) | ((unsigned int)f2bf(a1 * inv) << 16);
        p.y = (unsigned int)f2bf(a2 * inv) | ((unsigned int)f2bf(a3 * inv) << 16);
        p.z = (unsigned int)f2bf(a4 * inv) | ((unsigned int)f2bf(a5 * inv) << 16);
        p.w = (unsigned int)f2bf(a6 * inv) | ((unsigned int)f2bf(a7 * inv) << 16);
        *(uint4*)(mean + ((size_t)node << 7) + l * 8) = p;
    }
}

// ---------------- bf16 MFMA GEMM: 128 rows x 256 cols per block, 8 waves ----------------
// A = [A1 | A2] halves along K (ks<2 -> A1, else A2), row strides astr1/astr2.
// LDS rows: 8 x 16B granules, slot s of row r holds granule s ^ (r&7) (XOR swizzle
// on the global gather side; conflicts measured 0). Staged via global_load_lds.
// Wave grid 2x4: wave w -> rows (w>>2)*64.., cols (w&3)*64.. (4x4 MFMA tiles each).
__global__ __launch_bounds__(512) void gemm_mfma(
    const unsigned short* __restrict__ A1, const unsigned short* __restrict__ A2,
    int astr1, int astr2,
    const unsigned short* __restrict__ B,
    const float* __restrict__ biasBF, const float* __restrict__ biasF,
    unsigned short* __restrict__ outBF, float* __restrict__ outF,
    int N, int split, int reluBF) {
    __shared__ unsigned short As[128 * 64];   // 16 KB
    __shared__ unsigned short Bs[256 * 64];   // 32 KB (48 KB total -> 3 blocks/CU)
    int tid = threadIdx.x;
    int row0 = blockIdx.x * 128;
    int w = tid >> 6, lane = tid & 63;
    int wr = w >> 2, wc = w & 3;        // wave row-half / col-strip
    int q = lane >> 4, l16 = lane & 15;
    int rc = lane >> 3;                 // row within 8-row chunk
    int gsw = (lane & 7) ^ (rc & 7);    // swizzled granule to fetch

    f32x4 acc[4][4];
#pragma unroll
    for (int r = 0; r < 4; ++r)
#pragma unroll
        for (int c = 0; c < 4; ++c) acc[r][c] = (f32x4){0.f, 0.f, 0.f, 0.f};

    for (int ks = 0; ks < 4; ++ks) {
        int kbase = ks * 64;
        if (ks) __syncthreads();
        const unsigned short* Ap = (ks < 2) ? A1 : A2;
        int astr = (ks < 2) ? astr1 : astr2;
        int koff = (ks & 1) * 64;
        // A: 16 chunks of 8 rows; wave w stages chunks 2w, 2w+1
#pragma unroll
        for (int cc = 0; cc < 2; ++cc) {
            int c = w * 2 + cc;
            int grow = row0 + c * 8 + rc;
            if (grow > N - 1) grow = N - 1;   // clamp: garbage only pollutes unstored rows
            gl_lds16(Ap + (size_t)grow * astr + koff + gsw * 8, &As[c * 512]);
        }
        // B: 32 chunks of 8 rows; wave w stages chunks 4w..4w+3
#pragma unroll
        for (int cc = 0; cc < 4; ++cc) {
            int c = w * 4 + cc;
            int n = c * 8 + rc;
            gl_lds16(B + ((size_t)n << 8) + kbase + gsw * 8, &Bs[c * 512]);
        }
        __syncthreads();
#pragma unroll
        for (int k0 = 0; k0 < 64; k0 += 32) {
            int gb = (k0 >> 3) + q;
            int sl = gb ^ (l16 & 7);
            bf16x8 bfrag[4], afrag[4];
#pragma unroll
            for (int c = 0; c < 4; ++c) {
                int row = wc * 64 + c * 16 + l16;
                bfrag[c] = *(const bf16x8*)&Bs[row * 64 + sl * 8];
            }
#pragma unroll
            for (int r = 0; r < 4; ++r) {
                int row = wr * 64 + r * 16 + l16;
                afrag[r] = *(const bf16x8*)&As[row * 64 + sl * 8];
            }
#pragma unroll
            for (int r = 0; r < 4; ++r)
#pragma unroll
                for (int c = 0; c < 4; ++c)
                    acc[r][c] = __builtin_amdgcn_mfma_f32_16x16x32_bf16(afrag[r], bfrag[c], acc[r][c], 0, 0, 0);
        }
    }

    // epilogue: D col = lane&15, row = q*4 + reg
#pragma unroll
    for (int c = 0; c < 4; ++c) {
        int colg = wc * 64 + c * 16 + l16;
        bool isBF = (colg < split);
        float bb = 0.f;
        if (isBF) { if (biasBF) bb = biasBF[colg]; }
        else      bb = biasF[colg - split];
#pragma unroll
        for (int r = 0; r < 4; ++r) {
#pragma unroll
            for (int reg = 0; reg < 4; ++reg) {
                int rowg = row0 + wr * 64 + r * 16 + q * 4 + reg;
                if (rowg < N) {
                    float v = acc[r][c][reg] + bb;
                    if (isBF) {
                        if (reluBF) v = fmaxf(v, 0.f);
                        outBF[(size_t)rowg * split + colg] = f2bf(v);
                    } else {
                        outF[(size_t)rowg * (256 - split) + (colg - split)] = v;
                    }
                }
            }
        }
    }
}

// ---------------- agg2: out = mean_agg(P) + R (ushort nbr, LDS-staged lists) ----------------
__global__ __launch_bounds__(256) void agg2_kernel(
    const unsigned short* __restrict__ P, const float* __restrict__ R,
    const int* __restrict__ row_start, const int* __restrict__ deg,
    const unsigned short* __restrict__ nbr, float* __restrict__ out) {
    __shared__ unsigned short ll[16][80];
    int w = threadIdx.x >> 4;
    int l = threadIdx.x & 15;
    int node = blockIdx.x * 16 + w;
    if (node >= NN) return;
    int dg = deg[node];
    const unsigned short* gsl = nbr + row_start[node];
    float a0 = 0.f, a1 = 0.f, a2 = 0.f, a3 = 0.f, a4 = 0.f, a5 = 0.f, a6 = 0.f, a7 = 0.f;
    if (dg <= 80) {
        // stage this node's list into LDS once (wave-synchronous: worker = 16 lanes
        // of one wave); all subsequent index reads are LDS broadcasts instead of
        // 16x-replicated scalar VMEM loads on the dependent address path.
        for (int i = l; i < dg; i += 16) ll[w][i] = gsl[i];
        __builtin_amdgcn_wave_barrier();   // keep compiler from hoisting reads above writes
        const unsigned short* sl = &ll[w][0];
        int i = 0;
        for (; i + 8 <= dg; i += 8) {
            uint4 v[8];
#pragma unroll
            for (int u = 0; u < 8; ++u) {
                int s = sl[i + u];
                v[u] = *(const uint4*)(P + ((size_t)s << 7) + l * 8);
            }
#pragma unroll
            for (int u = 0; u < 8; ++u) {
                a0 += bf_lo(v[u].x); a1 += bf_hi(v[u].x);
                a2 += bf_lo(v[u].y); a3 += bf_hi(v[u].y);
                a4 += bf_lo(v[u].z); a5 += bf_hi(v[u].z);
                a6 += bf_lo(v[u].w); a7 += bf_hi(v[u].w);
            }
        }
        for (; i < dg; ++i) {
            int s = sl[i];
            uint4 v = *(const uint4*)(P + ((size_t)s << 7) + l * 8);
            a0 += bf_lo(v.x); a1 += bf_hi(v.x);
            a2 += bf_lo(v.y); a3 += bf_hi(v.y);
            a4 += bf_lo(v.z); a5 += bf_hi(v.z);
            a6 += bf_lo(v.w); a7 += bf_hi(v.w);
        }
    } else {
        // essentially-never path for this dataset (max degree ~40); correctness fallback
        for (int i = 0; i < dg; ++i) {
            int s = gsl[i];
            uint4 v = *(const uint4*)(P + ((size_t)s << 7) + l * 8);
            a0 += bf_lo(v.x); a1 += bf_hi(v.x);
            a2 += bf_lo(v.y); a3 += bf_hi(v.y);
            a4 += bf_lo(v.z); a5 += bf_hi(v.z);
            a6 += bf_lo(v.w); a7 += bf_hi(v.w);
        }
    }
    float inv = 1.0f / (float)(dg > 1 ? dg : 1);
    const float* rrow = R + ((size_t)node << 7) + l * 8;
    float4 r0 = *(const float4*)rrow;
    float4 r1 = *(const float4*)(rrow + 4);
    float4 o0, o1;
    o0.x = a0 * inv + r0.x; o0.y = a1 * inv + r0.y;
    o0.z = a2 * inv + r0.z; o0.w = a3 * inv + r0.w;
    o1.x = a4 * inv + r1.x; o1.y = a5 * inv + r1.y;
    o1.z = a6 * inv + r1.z; o1.w = a7 * inv + r1.w;
    float* orow = out + ((size_t)node << 7) + l * 8;
    *(float4*)orow = o0;
    *(float4*)(orow + 4) = o1;
}

extern "C" void kernel_launch(void* const* d_in, const int* in_sizes, int n_in,
                              void* d_out, int out_size, void* d_ws, size_t ws_size,
                              hipStream_t stream) {
    const float* x    = (const float*)d_in[0];
    const int*   edges = (const int*)d_in[1];
    const float* W1_l = (const float*)d_in[2];
    const float* b1   = (const float*)d_in[3];
    const float* W1_r = (const float*)d_in[4];
    const float* W2_l = (const float*)d_in[5];
    const float* b2   = (const float*)d_in[6];
    const float* W2_r = (const float*)d_in[7];
    float* out = (float*)d_out;

    const int N = NN;
    auto al = [](size_t v) { return (v + 255) & ~(size_t)255; };
    char* ws = (char*)d_ws;
    size_t o = 0;
    int* bcur = (int*)(ws + o); o += al((size_t)NBK * 4);
    unsigned int* packed = (unsigned int*)(ws + o); o += al((size_t)NBK * BUCKCAP * 4);
    unsigned short* nbr = (unsigned short*)(ws + o); o += al((size_t)NBK * BUCKCAP * 2);
    int* row_start = (int*)(ws + o); o += al((size_t)N * 4);
    int* deg       = (int*)(ws + o); o += al((size_t)N * 4);
    unsigned short* x_bf  = (unsigned short*)(ws + o); o += al((size_t)N * 128 * 2);
    unsigned short* mean1 = (unsigned short*)(ws + o); o += al((size_t)N * 128 * 2);
    unsigned short* h_bf  = (unsigned short*)(ws + o); o += al((size_t)N * 256 * 2);
    unsigned short* P_bf  = (unsigned short*)(ws + o); o += al((size_t)N * 128 * 2);
    float*          R_f   = (float*)(ws + o);          o += al((size_t)N * 128 * 4);
    unsigned short* B1    = (unsigned short*)(ws + o); o += al((size_t)256 * 256 * 2);
    unsigned short* B2    = (unsigned short*)(ws + o); o += al((size_t)256 * 256 * 2);

    // 1) zero bucket cursors (memset node, not a kernel dispatch)
    hipMemsetAsync(bcur, 0, (size_t)NBK * sizeof(int), stream);
    // 2) bin-scatter + B1/B2 pack + cast_x in one dispatch
    mega_kernel<<<FILL_NB + PACK_NB + CAST_NB, 256, 0, stream>>>(
        edges, bcur, packed, x, x_bf, W1_l, W1_r, W2_l, W2_r, B1, B2);
    // 3) per-bucket counting sort + mean1 aggregation (lists in LDS), CSR out for agg2
    pass2agg1_kernel<<<NBK, 512, 0, stream>>>(packed, bcur, x_bf, nbr, row_start, deg, mean1);
    // 4) h = relu([mean1||x_bf] @ B1^T + b1)  (bf16)
    gemm_mfma<<<(N + 127) / 128, 512, 0, stream>>>(mean1, x_bf, 128, 128, B1, b1, b1,
                                                   h_bf, (float*)nullptr, N, 256, 1);
    // 5) [P||R] = h @ B2^T ; P bf16 (no bias), R f32 (+b2)
    gemm_mfma<<<(N + 127) / 128, 512, 0, stream>>>(h_bf, h_bf + 128, 256, 256, B2,
                                                   (float*)nullptr, b2, P_bf, R_f, N, 128, 0);
    // 6) out = mean_agg(P) + R
    agg2_kernel<<<(N + 15) / 16, 256, 0, stream>>>(P_bf, R_f, row_start, deg, nbr, out);
}